// Round 5
// baseline (197.392 us; speedup 1.0000x reference)
//
#include <hip/hip_runtime.h>

// RelScaleAttend: b=4, 16 heads, s=1024 (32x32 img), d=64. Single fused kernel.
// Block = (h-pair, bh): 64 queries, 4 waves x 16 queries. K-tile = 64 keys,
// DOUBLE-BUFFERED LDS with ONE barrier per tile:
//   iter kt: COMPUTE from buf[kt&1]  ->  STAGE tile kt+1 into buf[~kt&1]
//            -> issue global loads for tile kt+2 -> lgkmcnt(0)+s_barrier.
// ds_reads precede ds_writes in program order, so in-order lgkm never makes
// an MFMA wait on staging; the vmcnt wait (inside STAGE) has ~1.5 iterations
// of load slack. 16 barrier-phases total (was 32 in R0-R3).
//
// LDS = 40960 B exactly -> 4 blocks/CU, whole 1024-block grid co-resident
// (R4 showed per-block latency halves with phase count but a 3+1 residency
// split ate the gain; this kernel removes the split AND halves phases again).
// Pads removed via XOR swizzle byte ^= (row&7)<<4 on 128-B rows:
//   RelH [64][32] f32 swz (8192) | arena 32768:
//     phase0: Ql 64x68 f32 [0,17408) | RelW 64x34 [17408,26112) | MH [26112,27136)
//     phase1: buf b @ b*16384: K [64][64] bf16 swz | V col-major [64][64] bf16 swz
//   (aliases safe: Ql consumed before the post-phase0 __syncthreads; RelW/MH
//    consumed into registers before the prologue barrier; buf1 first written
//    after it.)
//
// SWAPPED-OPERAND QK^T (R3): s = mfma(kf, qf) => lane holds full query rows;
// softmax fully per-lane; PV A-fragment = lane's own p values (no P LDS).
// STATIC-max softmax: p = exp2(qk*SCALE2 + relh2 + relw2 - M[q]), exact math.
// XCD head-affinity swizzle keeps each head's 16 blocks on one XCD (L2 reuse).

#define SCALE2 0.18033688f   // 0.125 * log2(e)
#define LOG2E  1.44269504f

typedef float  f32x4  __attribute__((ext_vector_type(4)));
typedef __bf16 bf16x8 __attribute__((ext_vector_type(8)));
typedef __bf16 bf16x4 __attribute__((ext_vector_type(4)));

// Barrier with LDS-completion only; vmcnt deliberately left outstanding.
#define BAR_LGKM()  do {                                            \
    asm volatile("s_waitcnt lgkmcnt(0)" ::: "memory");              \
    __builtin_amdgcn_s_barrier();                                   \
} while (0)

__global__ __launch_bounds__(256, 4) void attn(
        const float* __restrict__ qg, const float* __restrict__ kg,
        const float* __restrict__ vg,
        const float* __restrict__ rph, const float* __restrict__ rpw,
        float* __restrict__ outg) {
    __shared__ float RelH[64 * 32];               // 8192 B, swizzled 128-B rows
    __shared__ __align__(16) char arena[32768];
    float* Ql   = (float*)arena;                  // phase0 [0,17408)
    float* RelW = (float*)(arena + 17408);        // phase0 [17408,26112), stride 34
    float* MH   = (float*)(arena + 26112);        // phase0 [26112,27136)

    const int tid  = threadIdx.x;
    const int w    = tid >> 6, lane = tid & 63;
    const int quad = lane >> 4, n16 = lane & 15;
    const int sw16 = (n16 & 7) << 4;              // read-side row swizzle

    // ---- XCD head-affinity swizzle ----
    const int idx = blockIdx.x;
    const int xc  = idx & 7;
    const int r_  = idx >> 3;
    const int hp  = r_ & 15;
    const int bh  = xc + ((r_ >> 4) << 3);

    const int bb = bh >> 4, nh = bh & 15;
    const int h0 = hp << 1;
    const int base = bb * 1048576 + nh * 64;      // per-head element base
    const int sq0  = h0 * 32;                     // first query row of block

    // ---- stage Q rows (fp32) into LDS, coalesced b128 ----
    {
        int r0 = tid >> 4, c0 = (tid & 15) << 2;
#pragma unroll
        for (int k = 0; k < 4; ++k) {
            int row = k * 16 + r0;
            f32x4 v = *(const f32x4*)(qg + base + (sq0 + row) * 1024 + c0);
            *(f32x4*)&Ql[row * 68 + c0] = v;
        }
    }
    __syncthreads();

    // ---- phase 0: rel tables (x log2e) + per-slot max ----
    {
        int ql = tid & 63, slot = tid >> 6;
        int isw = slot >> 1, khb = (slot & 1) << 4;
        int hh = h0 + (ql >> 5), wl = ql & 31;
        int row0 = (isw ? wl : hh) + 31 - khb;      // row_j = row0 - j
        const float* tp = (isw ? rpw : rph) + row0 * 64;
        const float* qrow = &Ql[ql * 68];
        float acc[16];
#pragma unroll
        for (int j = 0; j < 16; ++j) acc[j] = 0.f;
#pragma unroll 4
        for (int cq = 0; cq < 16; ++cq) {
            f32x4 qv = *(const f32x4*)(qrow + cq * 4);
#pragma unroll
            for (int j = 0; j < 16; ++j) {
                f32x4 tv = *(const f32x4*)(tp - j * 64 + cq * 4);
                acc[j] += qv.x * tv.x + qv.y * tv.y + qv.z * tv.z + qv.w * tv.w;
            }
        }
        float hmax = -1e30f;
        if (isw) {
            float* dst = RelW + ql * 34 + khb;
#pragma unroll
            for (int j = 0; j < 16; ++j) {
                float v = acc[j] * LOG2E;
                dst[j] = v;
                hmax = fmaxf(hmax, v);
            }
        } else {
            char* rowH = (char*)RelH + ql * 128;
            int swz = (ql & 7) << 4;
#pragma unroll
            for (int j = 0; j < 16; ++j) {
                float v = acc[j] * LOG2E;
                *(float*)(rowH + ((((khb + j) << 2)) ^ swz)) = v;
                hmax = fmaxf(hmax, v);
            }
        }
        MH[slot * 64 + ql] = hmax;
    }

    // ---- Q fragments (MFMA B-operand): lane holds Q[w*16+n16][quad*8+j]
    const int qn = w * 16 + n16;             // this lane's softmax query
    bf16x8 qf[2];
#pragma unroll
    for (int ch = 0; ch < 2; ++ch) {
        const float* qp = &Ql[qn * 68 + ch * 32 + quad * 8];
        f32x4 a = ((const f32x4*)qp)[0];
        f32x4 b = ((const f32x4*)qp)[1];
        bf16x8 t;
        t[0] = (__bf16)a.x; t[1] = (__bf16)a.y; t[2] = (__bf16)a.z; t[3] = (__bf16)a.w;
        t[4] = (__bf16)b.x; t[5] = (__bf16)b.y; t[6] = (__bf16)b.z; t[7] = (__bf16)b.w;
        qf[ch] = t;
    }
    __syncthreads();   // phase-0 writes visible; all waves' Ql reads done

    // ---- per-lane static max M and rwm2[i][r] = RelW[qn][i*16+quad*4+r] - M
    float rwm2[2][4];
    {
        float M = fmaxf(MH[qn], MH[64 + qn]) + fmaxf(MH[128 + qn], MH[192 + qn]);
#pragma unroll
        for (int i = 0; i < 2; ++i) {
            float2 u = *(const float2*)&RelW[qn * 34 + i * 16 + quad * 4];
            float2 v2 = *(const float2*)&RelW[qn * 34 + i * 16 + quad * 4 + 2];
            rwm2[i][0] = u.x - M;  rwm2[i][1] = u.y - M;
            rwm2[i][2] = v2.x - M; rwm2[i][3] = v2.y - M;
        }
    }

    float lr = 0.f;
    f32x4 oc[4];
#pragma unroll
    for (int i = 0; i < 4; ++i) oc[i] = (f32x4){0.f, 0.f, 0.f, 0.f};

    const int krow = tid >> 3;                    // K staging row (0..31)
    const int kc0  = (tid & 7) << 3;              // K staging dim  (elements)
    const int kc0b = (tid & 7) << 4;              // ... in bytes
    const int kswz = (krow & 7) << 4;             // write-side row swizzle
    const int vc = tid & 63, vk0 = (tid >> 6) << 4;  // V staging: col, 16 keys/wave
    const int vswz = (vc & 7) << 4;

    // ---- register prefetch buffers ----
    f32x4 ka[2], kb4[2];
    float vv[16];

    auto LOADREGS = [&](int t) {
#pragma unroll
        for (int h = 0; h < 2; ++h) {
            const float* kp = kg + base + (t * 64 + krow + h * 32) * 1024 + kc0;
            ka[h]  = ((const f32x4*)kp)[0];
            kb4[h] = ((const f32x4*)kp)[1];
        }
#pragma unroll
        for (int j = 0; j < 16; ++j)
            vv[j] = vg[base + (t * 64 + vk0 + j) * 1024 + vc];
    };

    auto STAGE = [&](int b) {
        char* kbase = arena + b * 16384;
        char* vbase = kbase + 8192;
#pragma unroll
        for (int h = 0; h < 2; ++h) {
            bf16x8 t;
            t[0] = (__bf16)ka[h].x;  t[1] = (__bf16)ka[h].y;
            t[2] = (__bf16)ka[h].z;  t[3] = (__bf16)ka[h].w;
            t[4] = (__bf16)kb4[h].x; t[5] = (__bf16)kb4[h].y;
            t[6] = (__bf16)kb4[h].z; t[7] = (__bf16)kb4[h].w;
            *(bf16x8*)(kbase + (krow + h * 32) * 128 + (kc0b ^ kswz)) = t;
        }
#pragma unroll
        for (int m = 0; m < 4; ++m) {
            bf16x4 p4;
            p4[0] = (__bf16)vv[4 * m];     p4[1] = (__bf16)vv[4 * m + 1];
            p4[2] = (__bf16)vv[4 * m + 2]; p4[3] = (__bf16)vv[4 * m + 3];
            *(bf16x4*)(vbase + vc * 128 + ((((vk0 + 4 * m) << 1)) ^ vswz)) = p4;
        }
    };

    // ---- prologue: tile0 -> buf0; tile1 -> regs; one barrier ----
    LOADREGS(0);
    STAGE(0);
    LOADREGS(1);
    BAR_LGKM();

    for (int kt = 0; kt < 16; ++kt) {
        const char* kbase = arena + (kt & 1) * 16384;
        const char* vbase = kbase + 8192;

        // ---- COMPUTE tile kt (all ds_reads precede this iter's ds_writes) ----
        // S^T = K Q^T : 8 MFMAs; s[g][r] = S[key=g*16+quad*4+r][query=qn]
        f32x4 s[4];
#pragma unroll
        for (int g = 0; g < 4; ++g) s[g] = (f32x4){0.f, 0.f, 0.f, 0.f};
#pragma unroll
        for (int ch = 0; ch < 2; ++ch)
#pragma unroll
            for (int g = 0; g < 4; ++g) {
                bf16x8 kf = *(const bf16x8*)(kbase + (g * 16 + n16) * 128
                                             + ((ch * 64 + quad * 16) ^ sw16));
                s[g] = __builtin_amdgcn_mfma_f32_16x16x32_bf16(kf, qf[ch], s[g], 0, 0, 0);
            }

        // static-max softmax, per-lane: kh = kt*2+(g>>1), kw = (g&1)*16+quad*4+r
        float2 rhp = *(const float2*)((const char*)RelH + qn * 128 + ((kt * 8) ^ sw16));
        float p[4][4];
#pragma unroll
        for (int g = 0; g < 4; ++g) {
            const float rbase = (g >= 2) ? rhp.y : rhp.x;
#pragma unroll
            for (int r = 0; r < 4; ++r)
                p[g][r] = __builtin_amdgcn_exp2f(fmaf(s[g][r], SCALE2, rbase + rwm2[g & 1][r]));
        }
#pragma unroll
        for (int g = 0; g < 4; ++g)
            lr += ((p[g][0] + p[g][1]) + (p[g][2] + p[g][3]));

        // PV A-fragments: lane's own p values (zero shuffle)
        bf16x8 pf[2];
#pragma unroll
        for (int ko = 0; ko < 2; ++ko) {
            bf16x8 t;
            t[0] = (__bf16)p[2 * ko][0];     t[1] = (__bf16)p[2 * ko][1];
            t[2] = (__bf16)p[2 * ko][2];     t[3] = (__bf16)p[2 * ko][3];
            t[4] = (__bf16)p[2 * ko + 1][0]; t[5] = (__bf16)p[2 * ko + 1][1];
            t[6] = (__bf16)p[2 * ko + 1][2]; t[7] = (__bf16)p[2 * ko + 1][3];
            pf[ko] = t;
        }

        // O += P V : B-fragment from col-major swizzled Vl
#pragma unroll
        for (int ko = 0; ko < 2; ++ko)
#pragma unroll
            for (int cn = 0; cn < 4; ++cn) {
                const char* vb = vbase + (cn * 16 + n16) * 128;
                bf16x4 a = *(const bf16x4*)(vb + ((ko * 64 + quad * 8) ^ sw16));
                bf16x4 b = *(const bf16x4*)(vb + ((ko * 64 + quad * 8 + 32) ^ sw16));
                bf16x8 vf;
                vf[0] = a[0]; vf[1] = a[1]; vf[2] = a[2]; vf[3] = a[3];
                vf[4] = b[0]; vf[5] = b[1]; vf[6] = b[2]; vf[7] = b[3];
                oc[cn] = __builtin_amdgcn_mfma_f32_16x16x32_bf16(pf[ko], vf, oc[cn], 0, 0, 0);
            }

        // ---- STAGE tile kt+1 into the other buffer (vmcnt wait lands here,
        //      ~1.5 iterations after the loads were issued) ----
        STAGE((kt + 1) & 1);
        // ---- issue global loads for tile kt+2 (wrap; tail work is unused) ----
        LOADREGS((kt + 2) & 15);

        // single barrier: my reads of buf[kt&1] and writes of buf[~kt&1] done
        BAR_LGKM();
    }

    // ---- epilogue: full row-sum per query, redistribute, store ----
    lr += __shfl_xor(lr, 16);
    lr += __shfl_xor(lr, 32);
    float linv[4];
#pragma unroll
    for (int r = 0; r < 4; ++r)
        linv[r] = 1.f / __shfl(lr, quad * 4 + r, 64);   // L[query = quad*4+r]

    // oc[cn][r] = O[query = w*16 + quad*4 + r][dim = cn*16 + n16]
#pragma unroll
    for (int r = 0; r < 4; ++r) {
        int ob = base + (sq0 + w * 16 + quad * 4 + r) * 1024 + n16;
        outg[ob]      = oc[0][r] * linv[r];
        outg[ob + 16] = oc[1][r] * linv[r];
        outg[ob + 32] = oc[2][r] * linv[r];
        outg[ob + 48] = oc[3][r] * linv[r];
    }
}

extern "C" void kernel_launch(void* const* d_in, const int* in_sizes, int n_in,
                              void* d_out, int out_size, void* d_ws, size_t ws_size,
                              hipStream_t stream) {
    (void)in_sizes; (void)n_in; (void)out_size; (void)d_ws; (void)ws_size;
    const float* q   = (const float*)d_in[0];
    const float* k   = (const float*)d_in[1];
    const float* v   = (const float*)d_in[2];
    const float* rph = (const float*)d_in[3];
    const float* rpw = (const float*)d_in[4];
    attn<<<dim3(1024), 256, 0, stream>>>(q, k, v, rph, rpw, (float*)d_out);
}